// Round 10
// baseline (380.490 us; speedup 1.0000x reference)
//
#include <hip/hip_runtime.h>
#include <math.h>

#define NEG_SLOPE 0.2f
#define BIN_SHIFT 8          // dst bin = dst >> 8  (196 bins for N=50000)
#define CHUNK 8192           // edges per block in bin_hist / bin_scatter

typedef __fp16 h2t __attribute__((ext_vector_type(2)));
__device__ __forceinline__ unsigned pk2h(float a, float b) {
    h2t h = __builtin_amdgcn_cvt_pkrtz(a, b);
    return *(unsigned*)&h;
}

// acc += f16(lo/hi of h) * w   (f32 accumulate)
#define FMAMIX_LO(a, h, w) asm("v_fma_mix_f32 %0, %1, %2, %0 op_sel:[0,0,0] op_sel_hi:[1,0,0]" : "+v"(a) : "v"(h), "v"(w))
#define FMAMIX_HI(a, h, w) asm("v_fma_mix_f32 %0, %1, %2, %0 op_sel:[1,0,0] op_sel_hi:[1,0,0]" : "+v"(a) : "v"(h), "v"(w))

// x[i] = concat(pos[i] (3), emb[z[i]] (125))  -> [N,128]
__global__ void build_x(const float* __restrict__ pos, const int* __restrict__ z,
                        const float* __restrict__ emb, float* __restrict__ x, int n) {
    int id = blockIdx.x * blockDim.x + threadIdx.x;
    if (id >= n * 128) return;
    int node = id >> 7, k = id & 127;
    float v;
    if (k < 3) v = pos[node * 3 + k];
    else       v = emb[z[node] * 125 + (k - 3)];
    x[id] = v;
}

// ---- register-tiled f32 GEMM: Y = X @ W, plus f16 copy of Y ----------------
__global__ __launch_bounds__(256)
void gemm128_tiled(const float* __restrict__ X, const float* __restrict__ W,
                   float* __restrict__ Y, unsigned short* __restrict__ Yh, int n) {
    __shared__ float Xt[32][128];   // [k][row]
    __shared__ float Wl[32][128];   // [k][col]
    int tid = threadIdx.x;
    int tx = tid & 15, ty = tid >> 4;
    int row0 = blockIdx.x * 128;
    float acc[8][8];
    #pragma unroll
    for (int i = 0; i < 8; ++i)
        #pragma unroll
        for (int j = 0; j < 8; ++j) acc[i][j] = 0.f;

    for (int k0 = 0; k0 < 128; k0 += 32) {
        __syncthreads();
        #pragma unroll
        for (int i = 0; i < 4; ++i) {
            int f4 = tid + i * 256;
            int r = f4 >> 3, kp = (f4 & 7) << 2;
            int row = row0 + r;
            float4 v = (row < n) ? *(const float4*)(X + (size_t)row * 128 + k0 + kp)
                                 : make_float4(0.f, 0.f, 0.f, 0.f);
            Xt[kp + 0][r] = v.x; Xt[kp + 1][r] = v.y;
            Xt[kp + 2][r] = v.z; Xt[kp + 3][r] = v.w;
        }
        #pragma unroll
        for (int i = 0; i < 4; ++i) {
            int f4 = tid + i * 256;
            int kr = f4 >> 5, cp = (f4 & 31) << 2;
            *(float4*)(&Wl[kr][cp]) = *(const float4*)(W + (size_t)(k0 + kr) * 128 + cp);
        }
        __syncthreads();
        #pragma unroll 4
        for (int k = 0; k < 32; ++k) {
            float4 xa = *(float4*)(&Xt[k][ty * 8]);
            float4 xb = *(float4*)(&Xt[k][ty * 8 + 4]);
            float4 wa = *(float4*)(&Wl[k][tx * 4]);
            float4 wb = *(float4*)(&Wl[k][64 + tx * 4]);
            float xr[8] = {xa.x, xa.y, xa.z, xa.w, xb.x, xb.y, xb.z, xb.w};
            float wc[8] = {wa.x, wa.y, wa.z, wa.w, wb.x, wb.y, wb.z, wb.w};
            #pragma unroll
            for (int i = 0; i < 8; ++i)
                #pragma unroll
                for (int j = 0; j < 8; ++j) acc[i][j] += xr[i] * wc[j];
        }
    }
    #pragma unroll
    for (int i = 0; i < 8; ++i) {
        int row = row0 + ty * 8 + i;
        if (row >= n) break;
        *(float4*)(Y + (size_t)row * 128 + tx * 4) =
            make_float4(acc[i][0], acc[i][1], acc[i][2], acc[i][3]);
        *(float4*)(Y + (size_t)row * 128 + 64 + tx * 4) =
            make_float4(acc[i][4], acc[i][5], acc[i][6], acc[i][7]);
        uint2 qa, qb;
        qa.x = pk2h(acc[i][0], acc[i][1]);
        qa.y = pk2h(acc[i][2], acc[i][3]);
        qb.x = pk2h(acc[i][4], acc[i][5]);
        qb.y = pk2h(acc[i][6], acc[i][7]);
        *(uint2*)(Yh + (size_t)row * 128 + tx * 4)      = qa;
        *(uint2*)(Yh + (size_t)row * 128 + 64 + tx * 4) = qb;
    }
}

// Y[N,HOUT] = X[N,128] @ W[128,HOUT] (+bias). (final 32-col layer)
template <int HOUT, int ROWS>
__global__ void gemm_x128(const float* __restrict__ X, const float* __restrict__ W,
                          const float* __restrict__ bias, float* __restrict__ Y, int n) {
    __shared__ float Wl[128 * HOUT];
    __shared__ float Xl[ROWS][128];
    for (int i = threadIdx.x; i < 128 * HOUT; i += blockDim.x) Wl[i] = W[i];
    int row0 = blockIdx.x * ROWS;
    for (int i = threadIdx.x; i < ROWS * 128; i += blockDim.x) {
        int r = row0 + (i >> 7);
        Xl[i >> 7][i & 127] = (r < n) ? X[(size_t)r * 128 + (i & 127)] : 0.f;
    }
    __syncthreads();
    const int RPI = 256 / HOUT;
    int lr = threadIdx.x / HOUT;
    int j  = threadIdx.x % HOUT;
    for (int rr = lr; rr < ROWS; rr += RPI) {
        int r = row0 + rr;
        if (r >= n) break;
        float acc = bias ? bias[j] : 0.f;
        #pragma unroll 8
        for (int k = 0; k < 128; ++k) acc += Xl[rr][k] * Wl[k * HOUT + j];
        Y[(size_t)r * HOUT + j] = acc;
    }
}

// ssrc[i] = h[i].a_s ; sdst[i] = h[i].a_d  (one wave per node)
__global__ void node_dots(const float* __restrict__ h, const float* __restrict__ a_s,
                          const float* __restrict__ a_d, float* __restrict__ ssrc,
                          float* __restrict__ sdst, int n) {
    int gid = blockIdx.x * blockDim.x + threadIdx.x;
    int wid = gid >> 6, lane = gid & 63;
    if (wid >= n) return;
    float h0 = h[(size_t)wid * 128 + lane];
    float h1 = h[(size_t)wid * 128 + 64 + lane];
    float vs = h0 * a_s[lane] + h1 * a_s[64 + lane];
    float vd = h0 * a_d[lane] + h1 * a_d[64 + lane];
    #pragma unroll
    for (int o = 32; o; o >>= 1) { vs += __shfl_down(vs, o); vd += __shfl_down(vd, o); }
    if (lane == 0) { ssrc[wid] = vs; sdst[wid] = vd; }
}

// ------------- CSR build: two-level dst binning (no global hist atomics) ----

__global__ void bin_hist(const int* __restrict__ ei, int E, int n, int nbins,
                         int* __restrict__ binCnt) {
    __shared__ int h[256];
    int t = threadIdx.x;
    h[t] = 0;
    __syncthreads();
    int lo = blockIdx.x * CHUNK, hi = min(lo + CHUNK, E + n);
    for (int e = lo + t; e < hi; e += 256) {
        int d = (e < E) ? ei[E + e] : (e - E);
        atomicAdd(&h[d >> BIN_SHIFT], 1);
    }
    __syncthreads();
    if (t < nbins && h[t]) atomicAdd(&binCnt[t], h[t]);
}

__global__ void bin_scan(const int* __restrict__ binCnt, int nbins,
                         int* __restrict__ binBase, int* __restrict__ binCursor,
                         int* __restrict__ rowptr, int n, int Etot) {
    __shared__ int s[256];
    int t = threadIdx.x;
    int v = (t < nbins) ? binCnt[t] : 0;
    s[t] = v; __syncthreads();
    for (int o = 1; o < 256; o <<= 1) {
        int tv = (t >= o) ? s[t - o] : 0;
        __syncthreads();
        s[t] += tv;
        __syncthreads();
    }
    if (t < nbins) { binBase[t] = s[t] - v; binCursor[t] = s[t] - v; }
    if (t == 0) { binBase[nbins] = Etot; rowptr[n] = Etot; }
}

// pairs packed: (dst & 255) << 24 | src   (src < 2^24)
__global__ void bin_scatter(const int* __restrict__ ei, int E, int n, int nbins,
                            int* __restrict__ binCursor, unsigned* __restrict__ pairs) {
    __shared__ int h[256], cur[256];
    int t = threadIdx.x;
    h[t] = 0;
    __syncthreads();
    int lo = blockIdx.x * CHUNK, hi = min(lo + CHUNK, E + n);
    for (int e = lo + t; e < hi; e += 256) {
        int d = (e < E) ? ei[E + e] : (e - E);
        atomicAdd(&h[d >> BIN_SHIFT], 1);
    }
    __syncthreads();
    if (t < nbins) cur[t] = h[t] ? atomicAdd(&binCursor[t], h[t]) : 0;
    __syncthreads();
    for (int e = lo + t; e < hi; e += 256) {
        int s, d;
        if (e < E) { s = ei[e]; d = ei[E + e]; } else { s = d = e - E; }
        int p = atomicAdd(&cur[d >> BIN_SHIFT], 1);
        pairs[p] = ((unsigned)(d & 255) << 24) | (unsigned)s;
    }
}

__global__ void bin_finalize(const unsigned* __restrict__ pairs, const int* __restrict__ binBase,
                             int* __restrict__ rowptr, int* __restrict__ csr_src, int n) {
    int b = blockIdx.x;
    int lo = binBase[b], hi = binBase[b + 1];
    int d0 = b << BIN_SHIFT;
    int nd = min(256, n - d0);
    __shared__ int h[256], s[256], cur[256];
    int t = threadIdx.x;
    h[t] = 0;
    __syncthreads();
    for (int i = lo + t; i < hi; i += 256)
        atomicAdd(&h[pairs[i] >> 24], 1);
    __syncthreads();
    int v = h[t];
    s[t] = v; __syncthreads();
    for (int o = 1; o < 256; o <<= 1) {
        int tv = (t >= o) ? s[t - o] : 0;
        __syncthreads();
        s[t] += tv;
        __syncthreads();
    }
    int excl = lo + s[t] - v;
    if (t < nd) rowptr[d0 + t] = excl;
    cur[t] = excl;
    __syncthreads();
    for (int i = lo + t; i < hi; i += 256) {
        unsigned pr = pairs[i];
        int p = atomicAdd(&cur[pr >> 24], 1);
        csr_src[p] = (int)(pr & 0xFFFFFF);
    }
}

// ------------- fused GAT aggregation: one wave per dst node -----------------
// lane = 16*g + c. (w,src) staged in LDS per 64-edge chunk; inner loop does a
// broadcast ds_read_b64 + uint4 f16 row-chunk load + 8 v_fma_mix_f32.
__global__ void gat_gather(const int* __restrict__ rowptr, const int* __restrict__ csr_src,
                           const float* __restrict__ ssrc, const float* __restrict__ sdst,
                           const unsigned short* __restrict__ hu, const float* __restrict__ bias,
                           float* __restrict__ out, int n) {
    __shared__ uint2 stage[4][64];
    int wv = threadIdx.x >> 6;
    int wid = (blockIdx.x * blockDim.x + threadIdx.x) >> 6;
    int lane = threadIdx.x & 63;
    if (wid >= n) return;
    int beg = rowptr[wid], end = rowptr[wid + 1];
    float sd = sdst[wid];
    int g = lane >> 4;
    int c = lane & 15;

    // scores for first chunk kept in regs; max over all chunks
    int src0 = 0; float v0 = -INFINITY;
    {
        int i = beg + lane;
        if (i < end) {
            src0 = csr_src[i];
            float t = ssrc[src0] + sd;
            v0 = t > 0.f ? t : NEG_SLOPE * t;
        }
    }
    float m = v0;
    for (int base = beg + 64; base < end; base += 64) {
        int i = base + lane;
        float s = -INFINITY;
        if (i < end) {
            float t = ssrc[csr_src[i]] + sd;
            s = t > 0.f ? t : NEG_SLOPE * t;
        }
        m = fmaxf(m, s);
    }
    #pragma unroll
    for (int o = 32; o; o >>= 1) m = fmaxf(m, __shfl_xor(m, o));

    float acc[8];
    #pragma unroll
    for (int k = 0; k < 8; ++k) acc[k] = 0.f;
    float den = 0.f;

    for (int base = beg; base < end; base += 64) {
        int cnt = min(64, end - base);
        float w = 0.f; int src = 0;
        if (base == beg) {
            src = src0;
            w = (lane < cnt) ? expf(v0 - m) : 0.f;
        } else {
            int i = base + lane;
            if (i < end) {
                src = csr_src[i];
                float t = ssrc[src] + sd;
                t = t > 0.f ? t : NEG_SLOPE * t;
                w = expf(t - m);
            }
        }
        den += w;
        stage[wv][lane] = make_uint2(__float_as_uint(w), (unsigned)src);
        asm volatile("s_waitcnt lgkmcnt(0)" ::: "memory");
        int steps = (cnt + 3) >> 2;
        for (int j = 0; j < steps; ++j) {
            uint2 pr = stage[wv][j * 4 + g];
            float wj = __uint_as_float(pr.x);
            const uint4 hv = *(const uint4*)(hu + (size_t)pr.y * 128 + c * 8);
            FMAMIX_LO(acc[0], hv.x, wj); FMAMIX_HI(acc[1], hv.x, wj);
            FMAMIX_LO(acc[2], hv.y, wj); FMAMIX_HI(acc[3], hv.y, wj);
            FMAMIX_LO(acc[4], hv.z, wj); FMAMIX_HI(acc[5], hv.z, wj);
            FMAMIX_LO(acc[6], hv.w, wj); FMAMIX_HI(acc[7], hv.w, wj);
        }
    }
    #pragma unroll
    for (int o = 32; o; o >>= 1) den += __shfl_xor(den, o);
    #pragma unroll
    for (int k = 0; k < 8; ++k) {
        acc[k] += __shfl_xor(acc[k], 16);
        acc[k] += __shfl_xor(acc[k], 32);
    }
    if (g == 0) {
        float o8[8];
        #pragma unroll
        for (int k = 0; k < 8; ++k) {
            float v = acc[k] / den + bias[c * 8 + k];
            o8[k] = v > 0.f ? v : (expf(v) - 1.f);
        }
        float* op = out + (size_t)wid * 128 + c * 8;
        *(float4*)op       = make_float4(o8[0], o8[1], o8[2], o8[3]);
        *(float4*)(op + 4) = make_float4(o8[4], o8[5], o8[6], o8[7]);
    }
}

// ---------------- pooling: one block per graph (batch is sorted) ------------
__global__ void pool_graph(const float* __restrict__ y, const int* __restrict__ batch,
                           float* __restrict__ out, int n, int G) {
    int g = blockIdx.x;
    int lo = 0, hi = n;
    while (lo < hi) { int mid = (lo + hi) >> 1; if (batch[mid] < g) lo = mid + 1; else hi = mid; }
    int beg = lo;
    hi = n;
    while (lo < hi) { int mid = (lo + hi) >> 1; if (batch[mid] < g + 1) lo = mid + 1; else hi = mid; }
    int end = lo;

    int c = threadIdx.x & 31;
    int sub = threadIdx.x >> 5;
    float acc = 0.f;
    for (int node = beg + sub; node < end; node += 8)
        acc += y[(size_t)node * 32 + c];

    __shared__ float ls[8][32];
    ls[sub][c] = acc;
    __syncthreads();
    if (sub == 0) {
        float s = 0.f;
        #pragma unroll
        for (int k = 0; k < 8; ++k) s += ls[k][c];
        out[g * 32 + c] = s / fmaxf((float)(end - beg), 1.f);
    }
}

extern "C" void kernel_launch(void* const* d_in, const int* in_sizes, int n_in,
                              void* d_out, int out_size, void* d_ws, size_t ws_size,
                              hipStream_t stream) {
    const float* pos  = (const float*)d_in[0];
    const int*   z    = (const int*)d_in[1];
    const int*   ei   = (const int*)d_in[2];
    const int*   batch= (const int*)d_in[3];
    const float* emb  = (const float*)d_in[4];
    const float* W1   = (const float*)d_in[5];
    const float* a1s  = (const float*)d_in[6];
    const float* a1d  = (const float*)d_in[7];
    const float* b1   = (const float*)d_in[8];
    const float* W2   = (const float*)d_in[9];
    const float* a2s  = (const float*)d_in[10];
    const float* a2d  = (const float*)d_in[11];
    const float* b2   = (const float*)d_in[12];
    const float* Wlin = (const float*)d_in[13];
    const float* blin = (const float*)d_in[14];

    const int N = in_sizes[0] / 3;        // 50000
    const int E = in_sizes[2] / 2;        // 1600000
    const int Etot = E + N;
    const int G = out_size / 32;          // 64
    const int nbins = ((N - 1) >> BIN_SHIFT) + 1;   // 196

    char* ws = (char*)d_ws;
    size_t NB = (size_t)N * 128 * sizeof(float);
    float* buf0   = (float*)ws;                    // x / h2 / y  (pairs aliases this)
    float* buf1   = (float*)(ws + NB);             // h1 / out2
    float* buf2   = (float*)(ws + 2 * NB);         // out1 (=x for layer2)
    float* ssrc   = (float*)(ws + 3 * NB);
    float* sdst   = ssrc + N;
    int*   rowptr = (int*)(sdst + N);              // N+1
    int*   binCnt = rowptr + N + 1;                // 256
    int*   binBase= binCnt + 256;                  // 257
    int*   binCur = binBase + 257;                 // 256
    int*   csrs   = binCur + 256;                  // Etot
    uintptr_t hp  = (uintptr_t)(csrs + Etot);
    hp = (hp + 255) & ~(uintptr_t)255;             // 256B-align for uint4 rows
    unsigned short* hbf = (unsigned short*)hp;     // N*128 f16
    unsigned* pairs = (unsigned*)buf0;             // Etot uint (6.6MB < 25.6MB)

    const int TB = 256;
    dim3 blk(TB);
    int gElem  = (N * 128 + TB - 1) / TB;
    int gNodeW = ((size_t)N * 64 + TB - 1) / TB;
    int gGemmT = (N + 127) / 128;
    int gGemmO = (N + 63) / 64;
    int gGat   = (N + 3) / 4;
    int nchunk = (Etot + CHUNK - 1) / CHUNK;       // 202

    // ---------- CSR build: two-level dst binning ----------
    hipMemsetAsync(binCnt, 0, 256 * sizeof(int), stream);
    bin_hist<<<nchunk, blk, 0, stream>>>(ei, E, N, nbins, binCnt);
    bin_scan<<<1, blk, 0, stream>>>(binCnt, nbins, binBase, binCur, rowptr, N, Etot);
    bin_scatter<<<nchunk, blk, 0, stream>>>(ei, E, N, nbins, binCur, pairs);
    bin_finalize<<<nbins, blk, 0, stream>>>(pairs, binBase, rowptr, csrs, N);

    // ---------- layer 1 ----------
    build_x<<<gElem, blk, 0, stream>>>(pos, z, emb, buf0, N);
    gemm128_tiled<<<gGemmT, blk, 0, stream>>>(buf0, W1, buf1, hbf, N);
    node_dots<<<gNodeW, blk, 0, stream>>>(buf1, a1s, a1d, ssrc, sdst, N);
    gat_gather<<<gGat, blk, 0, stream>>>(rowptr, csrs, ssrc, sdst, hbf, b1, buf2, N);

    // ---------- layer 2 ----------
    gemm128_tiled<<<gGemmT, blk, 0, stream>>>(buf2, W2, buf0, hbf, N);
    node_dots<<<gNodeW, blk, 0, stream>>>(buf0, a2s, a2d, ssrc, sdst, N);
    gat_gather<<<gGat, blk, 0, stream>>>(rowptr, csrs, ssrc, sdst, hbf, b2, buf1, N);

    // ---------- linear + pool ----------
    gemm_x128<32, 64><<<gGemmO, blk, 0, stream>>>(buf1, Wlin, blin, buf0, N);
    pool_graph<<<G, blk, 0, stream>>>(buf0, batch, (float*)d_out, N, G);
}

// Round 11
// 363.391 us; speedup vs baseline: 1.0471x; 1.0471x over previous
//
#include <hip/hip_runtime.h>
#include <math.h>

#define NEG_SLOPE 0.2f
#define BIN_SHIFT 8          // dst bin = dst >> 8  (196 bins for N=50000)
#define CHUNK 8192           // edges per block in bin_hist / bin_scatter

typedef __fp16 h2t __attribute__((ext_vector_type(2)));
__device__ __forceinline__ unsigned pk2h(float a, float b) {
    h2t h = __builtin_amdgcn_cvt_pkrtz(a, b);
    return *(unsigned*)&h;
}

// acc += f16(lo/hi of h) * w   (f32 accumulate)
#define FMAMIX_LO(a, h, w) asm("v_fma_mix_f32 %0, %1, %2, %0 op_sel:[0,0,0] op_sel_hi:[1,0,0]" : "+v"(a) : "v"(h), "v"(w))
#define FMAMIX_HI(a, h, w) asm("v_fma_mix_f32 %0, %1, %2, %0 op_sel:[1,0,0] op_sel_hi:[1,0,0]" : "+v"(a) : "v"(h), "v"(w))

// x[i] = concat(pos[i] (3), emb[z[i]] (125))  -> [N,128]
__global__ void build_x(const float* __restrict__ pos, const int* __restrict__ z,
                        const float* __restrict__ emb, float* __restrict__ x, int n) {
    int id = blockIdx.x * blockDim.x + threadIdx.x;
    if (id >= n * 128) return;
    int node = id >> 7, k = id & 127;
    float v;
    if (k < 3) v = pos[node * 3 + k];
    else       v = emb[z[node] * 125 + (k - 3)];
    x[id] = v;
}

// ---- register-tiled f32 GEMM + fused node_dots epilogue --------------------
// Writes only the f16 copy of h; ssrc/sdst computed from the acc tile.
__global__ __launch_bounds__(256)
void gemm128_fused(const float* __restrict__ X, const float* __restrict__ W,
                   const float* __restrict__ a_s, const float* __restrict__ a_d,
                   unsigned short* __restrict__ Yh,
                   float* __restrict__ ssrc, float* __restrict__ sdst, int n) {
    __shared__ float Xt[32][128];   // [k][row]
    __shared__ float Wl[32][128];   // [k][col]
    __shared__ float As[128], Ad[128];
    int tid = threadIdx.x;
    if (tid < 128) As[tid] = a_s[tid];
    else           Ad[tid - 128] = a_d[tid - 128];
    int tx = tid & 15, ty = tid >> 4;
    int row0 = blockIdx.x * 128;
    float acc[8][8];
    #pragma unroll
    for (int i = 0; i < 8; ++i)
        #pragma unroll
        for (int j = 0; j < 8; ++j) acc[i][j] = 0.f;

    for (int k0 = 0; k0 < 128; k0 += 32) {
        __syncthreads();
        #pragma unroll
        for (int i = 0; i < 4; ++i) {
            int f4 = tid + i * 256;
            int r = f4 >> 3, kp = (f4 & 7) << 2;
            int row = row0 + r;
            float4 v = (row < n) ? *(const float4*)(X + (size_t)row * 128 + k0 + kp)
                                 : make_float4(0.f, 0.f, 0.f, 0.f);
            Xt[kp + 0][r] = v.x; Xt[kp + 1][r] = v.y;
            Xt[kp + 2][r] = v.z; Xt[kp + 3][r] = v.w;
        }
        #pragma unroll
        for (int i = 0; i < 4; ++i) {
            int f4 = tid + i * 256;
            int kr = f4 >> 5, cp = (f4 & 31) << 2;
            *(float4*)(&Wl[kr][cp]) = *(const float4*)(W + (size_t)(k0 + kr) * 128 + cp);
        }
        __syncthreads();
        #pragma unroll 4
        for (int k = 0; k < 32; ++k) {
            float4 xa = *(float4*)(&Xt[k][ty * 8]);
            float4 xb = *(float4*)(&Xt[k][ty * 8 + 4]);
            float4 wa = *(float4*)(&Wl[k][tx * 4]);
            float4 wb = *(float4*)(&Wl[k][64 + tx * 4]);
            float xr[8] = {xa.x, xa.y, xa.z, xa.w, xb.x, xb.y, xb.z, xb.w};
            float wc[8] = {wa.x, wa.y, wa.z, wa.w, wb.x, wb.y, wb.z, wb.w};
            #pragma unroll
            for (int i = 0; i < 8; ++i)
                #pragma unroll
                for (int j = 0; j < 8; ++j) acc[i][j] += xr[i] * wc[j];
        }
    }
    #pragma unroll
    for (int i = 0; i < 8; ++i) {
        int row = row0 + ty * 8 + i;
        if (row >= n) break;
        uint2 qa, qb;
        qa.x = pk2h(acc[i][0], acc[i][1]);
        qa.y = pk2h(acc[i][2], acc[i][3]);
        qb.x = pk2h(acc[i][4], acc[i][5]);
        qb.y = pk2h(acc[i][6], acc[i][7]);
        *(uint2*)(Yh + (size_t)row * 128 + tx * 4)      = qa;
        *(uint2*)(Yh + (size_t)row * 128 + 64 + tx * 4) = qb;
        // fused node_dots: partial dot over this thread's 8 cols, reduce over tx group
        float ds = 0.f, dd = 0.f;
        #pragma unroll
        for (int j = 0; j < 4; ++j) {
            ds += acc[i][j] * As[tx * 4 + j] + acc[i][4 + j] * As[64 + tx * 4 + j];
            dd += acc[i][j] * Ad[tx * 4 + j] + acc[i][4 + j] * Ad[64 + tx * 4 + j];
        }
        #pragma unroll
        for (int o = 1; o < 16; o <<= 1) {
            ds += __shfl_xor(ds, o);
            dd += __shfl_xor(dd, o);
        }
        if (tx == 0) { ssrc[row] = ds; sdst[row] = dd; }
    }
}

// Y[N,HOUT] = X[N,128] @ W[128,HOUT] (+bias). (final 32-col layer)
template <int HOUT, int ROWS>
__global__ void gemm_x128(const float* __restrict__ X, const float* __restrict__ W,
                          const float* __restrict__ bias, float* __restrict__ Y, int n) {
    __shared__ float Wl[128 * HOUT];
    __shared__ float Xl[ROWS][128];
    for (int i = threadIdx.x; i < 128 * HOUT; i += blockDim.x) Wl[i] = W[i];
    int row0 = blockIdx.x * ROWS;
    for (int i = threadIdx.x; i < ROWS * 128; i += blockDim.x) {
        int r = row0 + (i >> 7);
        Xl[i >> 7][i & 127] = (r < n) ? X[(size_t)r * 128 + (i & 127)] : 0.f;
    }
    __syncthreads();
    const int RPI = 256 / HOUT;
    int lr = threadIdx.x / HOUT;
    int j  = threadIdx.x % HOUT;
    for (int rr = lr; rr < ROWS; rr += RPI) {
        int r = row0 + rr;
        if (r >= n) break;
        float acc = bias ? bias[j] : 0.f;
        #pragma unroll 8
        for (int k = 0; k < 128; ++k) acc += Xl[rr][k] * Wl[k * HOUT + j];
        Y[(size_t)r * HOUT + j] = acc;
    }
}

// ------------- CSR build: two-level dst binning (no global hist atomics) ----

__global__ void bin_hist(const int* __restrict__ ei, int E, int n, int nbins,
                         int* __restrict__ binCnt) {
    __shared__ int h[256];
    int t = threadIdx.x;
    h[t] = 0;
    __syncthreads();
    int lo = blockIdx.x * CHUNK, hi = min(lo + CHUNK, E + n);
    for (int e = lo + t; e < hi; e += 256) {
        int d = (e < E) ? ei[E + e] : (e - E);
        atomicAdd(&h[d >> BIN_SHIFT], 1);
    }
    __syncthreads();
    if (t < nbins && h[t]) atomicAdd(&binCnt[t], h[t]);
}

__global__ void bin_scan(const int* __restrict__ binCnt, int nbins,
                         int* __restrict__ binBase, int* __restrict__ binCursor,
                         int* __restrict__ rowptr, int n, int Etot) {
    __shared__ int s[256];
    int t = threadIdx.x;
    int v = (t < nbins) ? binCnt[t] : 0;
    s[t] = v; __syncthreads();
    for (int o = 1; o < 256; o <<= 1) {
        int tv = (t >= o) ? s[t - o] : 0;
        __syncthreads();
        s[t] += tv;
        __syncthreads();
    }
    if (t < nbins) { binBase[t] = s[t] - v; binCursor[t] = s[t] - v; }
    if (t == 0) { binBase[nbins] = Etot; rowptr[n] = Etot; }
}

// pairs packed: (dst & 255) << 24 | src   (src < 2^24)
__global__ void bin_scatter(const int* __restrict__ ei, int E, int n, int nbins,
                            int* __restrict__ binCursor, unsigned* __restrict__ pairs) {
    __shared__ int h[256], cur[256];
    int t = threadIdx.x;
    h[t] = 0;
    __syncthreads();
    int lo = blockIdx.x * CHUNK, hi = min(lo + CHUNK, E + n);
    for (int e = lo + t; e < hi; e += 256) {
        int d = (e < E) ? ei[E + e] : (e - E);
        atomicAdd(&h[d >> BIN_SHIFT], 1);
    }
    __syncthreads();
    if (t < nbins) cur[t] = h[t] ? atomicAdd(&binCursor[t], h[t]) : 0;
    __syncthreads();
    for (int e = lo + t; e < hi; e += 256) {
        int s, d;
        if (e < E) { s = ei[e]; d = ei[E + e]; } else { s = d = e - E; }
        int p = atomicAdd(&cur[d >> BIN_SHIFT], 1);
        pairs[p] = ((unsigned)(d & 255) << 24) | (unsigned)s;
    }
}

__global__ void bin_finalize(const unsigned* __restrict__ pairs, const int* __restrict__ binBase,
                             int* __restrict__ rowptr, int* __restrict__ csr_src, int n) {
    int b = blockIdx.x;
    int lo = binBase[b], hi = binBase[b + 1];
    int d0 = b << BIN_SHIFT;
    int nd = min(256, n - d0);
    __shared__ int h[256], s[256], cur[256];
    int t = threadIdx.x;
    h[t] = 0;
    __syncthreads();
    for (int i = lo + t; i < hi; i += 256)
        atomicAdd(&h[pairs[i] >> 24], 1);
    __syncthreads();
    int v = h[t];
    s[t] = v; __syncthreads();
    for (int o = 1; o < 256; o <<= 1) {
        int tv = (t >= o) ? s[t - o] : 0;
        __syncthreads();
        s[t] += tv;
        __syncthreads();
    }
    int excl = lo + s[t] - v;
    if (t < nd) rowptr[d0 + t] = excl;
    cur[t] = excl;
    __syncthreads();
    for (int i = lo + t; i < hi; i += 256) {
        unsigned pr = pairs[i];
        int p = atomicAdd(&cur[pr >> 24], 1);
        csr_src[p] = (int)(pr & 0xFFFFFF);
    }
}

// ------------- fused GAT aggregation: one wave per dst node -----------------
// lane = 16*g + c. (w,src) staged in LDS per 64-edge chunk; j-loop unrolled 4x
// so ~16 independent 16B row-loads are in flight per wave.
__global__ void gat_gather(const int* __restrict__ rowptr, const int* __restrict__ csr_src,
                           const float* __restrict__ ssrc, const float* __restrict__ sdst,
                           const unsigned short* __restrict__ hu, const float* __restrict__ bias,
                           float* __restrict__ out, int n) {
    __shared__ uint2 stage[4][64];
    int wv = threadIdx.x >> 6;
    int wid = (blockIdx.x * blockDim.x + threadIdx.x) >> 6;
    int lane = threadIdx.x & 63;
    if (wid >= n) return;
    int beg = rowptr[wid], end = rowptr[wid + 1];
    float sd = sdst[wid];
    int g = lane >> 4;
    int c = lane & 15;

    // scores for first chunk kept in regs; max over all chunks
    int src0 = 0; float v0 = -INFINITY;
    {
        int i = beg + lane;
        if (i < end) {
            src0 = csr_src[i];
            float t = ssrc[src0] + sd;
            v0 = t > 0.f ? t : NEG_SLOPE * t;
        }
    }
    float m = v0;
    for (int base = beg + 64; base < end; base += 64) {
        int i = base + lane;
        float s = -INFINITY;
        if (i < end) {
            float t = ssrc[csr_src[i]] + sd;
            s = t > 0.f ? t : NEG_SLOPE * t;
        }
        m = fmaxf(m, s);
    }
    #pragma unroll
    for (int o = 32; o; o >>= 1) m = fmaxf(m, __shfl_xor(m, o));

    float acc[8];
    #pragma unroll
    for (int k = 0; k < 8; ++k) acc[k] = 0.f;
    float den = 0.f;

    for (int base = beg; base < end; base += 64) {
        int cnt = min(64, end - base);
        float w = 0.f; int src = 0;
        if (base == beg) {
            src = src0;
            w = (lane < cnt) ? expf(v0 - m) : 0.f;
        } else {
            int i = base + lane;
            if (i < end) {
                src = csr_src[i];
                float t = ssrc[src] + sd;
                t = t > 0.f ? t : NEG_SLOPE * t;
                w = expf(t - m);
            }
        }
        den += w;
        stage[wv][lane] = make_uint2(__float_as_uint(w), (unsigned)src);
        asm volatile("s_waitcnt lgkmcnt(0)" ::: "memory");
        int steps = (cnt + 3) >> 2;
        #pragma unroll 4
        for (int j = 0; j < steps; ++j) {
            uint2 pr = stage[wv][j * 4 + g];
            float wj = __uint_as_float(pr.x);
            const uint4 hv = *(const uint4*)(hu + (size_t)pr.y * 128 + c * 8);
            FMAMIX_LO(acc[0], hv.x, wj); FMAMIX_HI(acc[1], hv.x, wj);
            FMAMIX_LO(acc[2], hv.y, wj); FMAMIX_HI(acc[3], hv.y, wj);
            FMAMIX_LO(acc[4], hv.z, wj); FMAMIX_HI(acc[5], hv.z, wj);
            FMAMIX_LO(acc[6], hv.w, wj); FMAMIX_HI(acc[7], hv.w, wj);
        }
    }
    #pragma unroll
    for (int o = 32; o; o >>= 1) den += __shfl_xor(den, o);
    #pragma unroll
    for (int k = 0; k < 8; ++k) {
        acc[k] += __shfl_xor(acc[k], 16);
        acc[k] += __shfl_xor(acc[k], 32);
    }
    if (g == 0) {
        float o8[8];
        #pragma unroll
        for (int k = 0; k < 8; ++k) {
            float v = acc[k] / den + bias[c * 8 + k];
            o8[k] = v > 0.f ? v : (expf(v) - 1.f);
        }
        float* op = out + (size_t)wid * 128 + c * 8;
        *(float4*)op       = make_float4(o8[0], o8[1], o8[2], o8[3]);
        *(float4*)(op + 4) = make_float4(o8[4], o8[5], o8[6], o8[7]);
    }
}

// ---------------- pooling: one block per graph (batch is sorted) ------------
__global__ void pool_graph(const float* __restrict__ y, const int* __restrict__ batch,
                           float* __restrict__ out, int n, int G) {
    int g = blockIdx.x;
    int lo = 0, hi = n;
    while (lo < hi) { int mid = (lo + hi) >> 1; if (batch[mid] < g) lo = mid + 1; else hi = mid; }
    int beg = lo;
    hi = n;
    while (lo < hi) { int mid = (lo + hi) >> 1; if (batch[mid] < g + 1) lo = mid + 1; else hi = mid; }
    int end = lo;

    int c = threadIdx.x & 31;
    int sub = threadIdx.x >> 5;
    float acc = 0.f;
    for (int node = beg + sub; node < end; node += 8)
        acc += y[(size_t)node * 32 + c];

    __shared__ float ls[8][32];
    ls[sub][c] = acc;
    __syncthreads();
    if (sub == 0) {
        float s = 0.f;
        #pragma unroll
        for (int k = 0; k < 8; ++k) s += ls[k][c];
        out[g * 32 + c] = s / fmaxf((float)(end - beg), 1.f);
    }
}

extern "C" void kernel_launch(void* const* d_in, const int* in_sizes, int n_in,
                              void* d_out, int out_size, void* d_ws, size_t ws_size,
                              hipStream_t stream) {
    const float* pos  = (const float*)d_in[0];
    const int*   z    = (const int*)d_in[1];
    const int*   ei   = (const int*)d_in[2];
    const int*   batch= (const int*)d_in[3];
    const float* emb  = (const float*)d_in[4];
    const float* W1   = (const float*)d_in[5];
    const float* a1s  = (const float*)d_in[6];
    const float* a1d  = (const float*)d_in[7];
    const float* b1   = (const float*)d_in[8];
    const float* W2   = (const float*)d_in[9];
    const float* a2s  = (const float*)d_in[10];
    const float* a2d  = (const float*)d_in[11];
    const float* b2   = (const float*)d_in[12];
    const float* Wlin = (const float*)d_in[13];
    const float* blin = (const float*)d_in[14];

    const int N = in_sizes[0] / 3;        // 50000
    const int E = in_sizes[2] / 2;        // 1600000
    const int Etot = E + N;
    const int G = out_size / 32;          // 64
    const int nbins = ((N - 1) >> BIN_SHIFT) + 1;   // 196

    char* ws = (char*)d_ws;
    size_t NB = (size_t)N * 128 * sizeof(float);
    float* buf0   = (float*)ws;                    // x / y  (pairs aliases this)
    float* buf1   = (float*)(ws + NB);             // out2
    float* buf2   = (float*)(ws + 2 * NB);         // out1 (=x for layer2)
    float* ssrc   = (float*)(ws + 3 * NB);
    float* sdst   = ssrc + N;
    int*   rowptr = (int*)(sdst + N);              // N+1
    int*   binCnt = rowptr + N + 1;                // 256
    int*   binBase= binCnt + 256;                  // 257
    int*   binCur = binBase + 257;                 // 256
    int*   csrs   = binCur + 256;                  // Etot
    uintptr_t hp  = (uintptr_t)(csrs + Etot);
    hp = (hp + 255) & ~(uintptr_t)255;             // 256B-align for uint4 rows
    unsigned short* hbf = (unsigned short*)hp;     // N*128 f16
    unsigned* pairs = (unsigned*)buf0;             // Etot uint (6.6MB < 25.6MB)

    const int TB = 256;
    dim3 blk(TB);
    int gElem  = (N * 128 + TB - 1) / TB;
    int gGemmT = (N + 127) / 128;
    int gGemmO = (N + 63) / 64;
    int gGat   = (N + 3) / 4;
    int nchunk = (Etot + CHUNK - 1) / CHUNK;       // 202

    // ---------- CSR build: two-level dst binning ----------
    hipMemsetAsync(binCnt, 0, 256 * sizeof(int), stream);
    bin_hist<<<nchunk, blk, 0, stream>>>(ei, E, N, nbins, binCnt);
    bin_scan<<<1, blk, 0, stream>>>(binCnt, nbins, binBase, binCur, rowptr, N, Etot);
    bin_scatter<<<nchunk, blk, 0, stream>>>(ei, E, N, nbins, binCur, pairs);
    bin_finalize<<<nbins, blk, 0, stream>>>(pairs, binBase, rowptr, csrs, N);

    // ---------- layer 1 ----------
    build_x<<<gElem, blk, 0, stream>>>(pos, z, emb, buf0, N);
    gemm128_fused<<<gGemmT, blk, 0, stream>>>(buf0, W1, a1s, a1d, hbf, ssrc, sdst, N);
    gat_gather<<<gGat, blk, 0, stream>>>(rowptr, csrs, ssrc, sdst, hbf, b1, buf2, N);

    // ---------- layer 2 ----------
    gemm128_fused<<<gGemmT, blk, 0, stream>>>(buf2, W2, a2s, a2d, hbf, ssrc, sdst, N);
    gat_gather<<<gGat, blk, 0, stream>>>(rowptr, csrs, ssrc, sdst, hbf, b2, buf1, N);

    // ---------- linear + pool ----------
    gemm_x128<32, 64><<<gGemmO, blk, 0, stream>>>(buf1, Wlin, blin, buf0, N);
    pool_graph<<<G, blk, 0, stream>>>(buf0, batch, (float*)d_out, N, G);
}

// Round 12
// 317.598 us; speedup vs baseline: 1.1980x; 1.1442x over previous
//
#include <hip/hip_runtime.h>
#include <math.h>

#define NEG_SLOPE 0.2f
#define BIN_SHIFT 8          // dst bin = dst >> 8  (196 bins for N=50000)
#define CHUNK 8192           // edges per block in bin_hist / bin_scatter

typedef __fp16 f16x4 __attribute__((ext_vector_type(4)));
typedef __fp16 f16x8 __attribute__((ext_vector_type(8)));
typedef float  f32x4 __attribute__((ext_vector_type(4)));

__device__ __forceinline__ unsigned pkh_rne(float a, float b) {
    __fp16 ha = (__fp16)a, hb = (__fp16)b;
    unsigned short ua, ub;
    __builtin_memcpy(&ua, &ha, 2);
    __builtin_memcpy(&ub, &hb, 2);
    return (unsigned)ua | ((unsigned)ub << 16);
}

// acc += f16(lo/hi of h) * w   (f32 accumulate)
#define FMAMIX_LO(a, h, w) asm("v_fma_mix_f32 %0, %1, %2, %0 op_sel:[0,0,0] op_sel_hi:[1,0,0]" : "+v"(a) : "v"(h), "v"(w))
#define FMAMIX_HI(a, h, w) asm("v_fma_mix_f32 %0, %1, %2, %0 op_sel:[1,0,0] op_sel_hi:[1,0,0]" : "+v"(a) : "v"(h), "v"(w))

// x[i] = concat(pos[i] (3), emb[z[i]] (125))  -> [N,128]
__global__ void build_x(const float* __restrict__ pos, const int* __restrict__ z,
                        const float* __restrict__ emb, float* __restrict__ x, int n) {
    int id = blockIdx.x * blockDim.x + threadIdx.x;
    if (id >= n * 128) return;
    int node = id >> 7, k = id & 127;
    float v;
    if (k < 3) v = pos[node * 3 + k];
    else       v = emb[z[node] * 125 + (k - 3)];
    x[id] = v;
}

// ---- MFMA f16 GEMM: Yh[f16] = X[f32] @ W[f32], fused node_dots epilogue ----
// block = 256 thr = 4 waves; 64 rows x 128 cols per block; K=128 in 4 chunks.
// LDS: WT = W^T [col][k] f16 swizzled; Xh = X [row][k] f16 swizzled.
__global__ __launch_bounds__(256)
void gemm128_mfma(const float* __restrict__ X, const float* __restrict__ W,
                  const float* __restrict__ a_s, const float* __restrict__ a_d,
                  unsigned short* __restrict__ Yh,
                  float* __restrict__ ssrc, float* __restrict__ sdst, int n) {
    __shared__ unsigned short WT[128 * 128];  // 32 KB
    __shared__ unsigned short Xh[64 * 128];   // 16 KB
    __shared__ float As[128], Ad[128];
    int tid = threadIdx.x;
    if (tid < 128) As[tid] = a_s[tid];
    else           Ad[tid - 128] = a_d[tid - 128];
    int r0 = blockIdx.x * 64;

    // stage W^T as f16 (u32 = 2 k's per col), swizzled byte ^= (col&7)<<3
    #pragma unroll
    for (int it = 0; it < 32; ++it) {
        int id = it * 256 + tid;            // 8192 u32 units
        int col = id & 127, kp = id >> 7;   // k = 2*kp, 2*kp+1
        float w0 = W[(size_t)(2 * kp) * 128 + col];
        float w1 = W[(size_t)(2 * kp + 1) * 128 + col];
        int byte = (col * 256 + kp * 4) ^ ((col & 7) << 3);
        *(unsigned*)((char*)WT + byte) = pkh_rne(w0, w1);
    }
    // stage X rows as f16, swizzled byte ^= (row&7)<<3
    #pragma unroll
    for (int it = 0; it < 16; ++it) {
        int id = it * 256 + tid;            // 4096 u32 units
        int row = id >> 6, c = id & 63;     // cols 2c, 2c+1
        int grow = r0 + row;
        float2 v = (grow < n) ? *(const float2*)(X + (size_t)grow * 128 + 2 * c)
                              : make_float2(0.f, 0.f);
        int byte = (row * 256 + c * 4) ^ ((row & 7) << 3);
        *(unsigned*)((char*)Xh + byte) = pkh_rne(v.x, v.y);
    }
    __syncthreads();

    int lane = tid & 63, wv = tid >> 6;
    int rL = (wv << 4) + (lane & 15);       // LDS row for A (0..63)
    int kg = lane >> 4;                     // 0..3
    f32x4 acc[8];
    #pragma unroll
    for (int t = 0; t < 8; ++t) acc[t] = (f32x4){0.f, 0.f, 0.f, 0.f};

    #pragma unroll
    for (int k0 = 0; k0 < 128; k0 += 32) {
        // A frag: k = k0 + kg*4 + j (j<4) ; k0+16+kg*4+(j-4) (j>=4)
        int abase = rL * 256;
        int aswz = (rL & 7) << 3;
        f16x4 alo = *(f16x4*)((char*)Xh + ((abase + (k0 + kg * 4) * 2) ^ aswz));
        f16x4 ahi = *(f16x4*)((char*)Xh + ((abase + (k0 + 16 + kg * 4) * 2) ^ aswz));
        f16x8 a = {alo[0], alo[1], alo[2], alo[3], ahi[0], ahi[1], ahi[2], ahi[3]};
        #pragma unroll
        for (int t = 0; t < 8; ++t) {
            int colL = (t << 4) + (lane & 15);
            int bbase = colL * 256;
            int bswz = (colL & 7) << 3;
            f16x4 blo = *(f16x4*)((char*)WT + ((bbase + (k0 + kg * 4) * 2) ^ bswz));
            f16x4 bhi = *(f16x4*)((char*)WT + ((bbase + (k0 + 16 + kg * 4) * 2) ^ bswz));
            f16x8 b = {blo[0], blo[1], blo[2], blo[3], bhi[0], bhi[1], bhi[2], bhi[3]};
            acc[t] = __builtin_amdgcn_mfma_f32_16x16x32_f16(a, b, acc[t], 0, 0, 0);
        }
    }

    // epilogue: C/D layout col = lane&15, row = kg*4 + i (within 16-row tile)
    int rowBase = r0 + (wv << 4) + kg * 4;
    float ds[4] = {0.f, 0.f, 0.f, 0.f}, dd[4] = {0.f, 0.f, 0.f, 0.f};
    #pragma unroll
    for (int t = 0; t < 8; ++t) {
        int colA = (t << 4) + (lane & 15);
        float as = As[colA], ad = Ad[colA];
        #pragma unroll
        for (int i = 0; i < 4; ++i) {
            int rowA = rowBase + i;
            if (rowA < n) {
                __fp16 hv = (__fp16)acc[t][i];
                *(__fp16*)(Yh + (size_t)rowA * 128 + colA) = hv;
            }
            ds[i] += acc[t][i] * as;
            dd[i] += acc[t][i] * ad;
        }
    }
    #pragma unroll
    for (int o = 1; o < 16; o <<= 1) {
        #pragma unroll
        for (int i = 0; i < 4; ++i) {
            ds[i] += __shfl_xor(ds[i], o);
            dd[i] += __shfl_xor(dd[i], o);
        }
    }
    if ((lane & 15) == 0) {
        #pragma unroll
        for (int i = 0; i < 4; ++i) {
            int rowA = rowBase + i;
            if (rowA < n) { ssrc[rowA] = ds[i]; sdst[rowA] = dd[i]; }
        }
    }
}

// ------------- CSR build: two-level dst binning (no global hist atomics) ----

__global__ void bin_hist(const int* __restrict__ ei, int E, int n, int nbins,
                         int* __restrict__ binCnt) {
    __shared__ int h[256];
    int t = threadIdx.x;
    h[t] = 0;
    __syncthreads();
    int lo = blockIdx.x * CHUNK, hi = min(lo + CHUNK, E + n);
    for (int e = lo + t; e < hi; e += 256) {
        int d = (e < E) ? ei[E + e] : (e - E);
        atomicAdd(&h[d >> BIN_SHIFT], 1);
    }
    __syncthreads();
    if (t < nbins && h[t]) atomicAdd(&binCnt[t], h[t]);
}

__global__ void bin_scan(const int* __restrict__ binCnt, int nbins,
                         int* __restrict__ binBase, int* __restrict__ binCursor,
                         int* __restrict__ rowptr, int n, int Etot) {
    __shared__ int s[256];
    int t = threadIdx.x;
    int v = (t < nbins) ? binCnt[t] : 0;
    s[t] = v; __syncthreads();
    for (int o = 1; o < 256; o <<= 1) {
        int tv = (t >= o) ? s[t - o] : 0;
        __syncthreads();
        s[t] += tv;
        __syncthreads();
    }
    if (t < nbins) { binBase[t] = s[t] - v; binCursor[t] = s[t] - v; }
    if (t == 0) { binBase[nbins] = Etot; rowptr[n] = Etot; }
}

// pairs packed: (dst & 255) << 24 | src   (src < 2^24)
__global__ void bin_scatter(const int* __restrict__ ei, int E, int n, int nbins,
                            int* __restrict__ binCursor, unsigned* __restrict__ pairs) {
    __shared__ int h[256], cur[256];
    int t = threadIdx.x;
    h[t] = 0;
    __syncthreads();
    int lo = blockIdx.x * CHUNK, hi = min(lo + CHUNK, E + n);
    for (int e = lo + t; e < hi; e += 256) {
        int d = (e < E) ? ei[E + e] : (e - E);
        atomicAdd(&h[d >> BIN_SHIFT], 1);
    }
    __syncthreads();
    if (t < nbins) cur[t] = h[t] ? atomicAdd(&binCursor[t], h[t]) : 0;
    __syncthreads();
    for (int e = lo + t; e < hi; e += 256) {
        int s, d;
        if (e < E) { s = ei[e]; d = ei[E + e]; } else { s = d = e - E; }
        int p = atomicAdd(&cur[d >> BIN_SHIFT], 1);
        pairs[p] = ((unsigned)(d & 255) << 24) | (unsigned)s;
    }
}

__global__ void bin_finalize(const unsigned* __restrict__ pairs, const int* __restrict__ binBase,
                             int* __restrict__ rowptr, int* __restrict__ csr_src, int n) {
    int b = blockIdx.x;
    int lo = binBase[b], hi = binBase[b + 1];
    int d0 = b << BIN_SHIFT;
    int nd = min(256, n - d0);
    __shared__ int h[256], s[256], cur[256];
    int t = threadIdx.x;
    h[t] = 0;
    __syncthreads();
    for (int i = lo + t; i < hi; i += 256)
        atomicAdd(&h[pairs[i] >> 24], 1);
    __syncthreads();
    int v = h[t];
    s[t] = v; __syncthreads();
    for (int o = 1; o < 256; o <<= 1) {
        int tv = (t >= o) ? s[t - o] : 0;
        __syncthreads();
        s[t] += tv;
        __syncthreads();
    }
    int excl = lo + s[t] - v;
    if (t < nd) rowptr[d0 + t] = excl;
    cur[t] = excl;
    __syncthreads();
    for (int i = lo + t; i < hi; i += 256) {
        unsigned pr = pairs[i];
        int p = atomicAdd(&cur[pr >> 24], 1);
        csr_src[p] = (int)(pr & 0xFFFFFF);
    }
}

// ------------- fused GAT aggregation: one wave per dst node -----------------
__global__ void gat_gather(const int* __restrict__ rowptr, const int* __restrict__ csr_src,
                           const float* __restrict__ ssrc, const float* __restrict__ sdst,
                           const unsigned short* __restrict__ hu, const float* __restrict__ bias,
                           float* __restrict__ out, int n) {
    __shared__ uint2 stage[4][64];
    int wv = threadIdx.x >> 6;
    int wid = (blockIdx.x * blockDim.x + threadIdx.x) >> 6;
    int lane = threadIdx.x & 63;
    if (wid >= n) return;
    int beg = rowptr[wid], end = rowptr[wid + 1];
    float sd = sdst[wid];
    int g = lane >> 4;
    int c = lane & 15;

    int src0 = 0; float v0 = -INFINITY;
    {
        int i = beg + lane;
        if (i < end) {
            src0 = csr_src[i];
            float t = ssrc[src0] + sd;
            v0 = t > 0.f ? t : NEG_SLOPE * t;
        }
    }
    float m = v0;
    for (int base = beg + 64; base < end; base += 64) {
        int i = base + lane;
        float s = -INFINITY;
        if (i < end) {
            float t = ssrc[csr_src[i]] + sd;
            s = t > 0.f ? t : NEG_SLOPE * t;
        }
        m = fmaxf(m, s);
    }
    #pragma unroll
    for (int o = 32; o; o >>= 1) m = fmaxf(m, __shfl_xor(m, o));

    float acc[8];
    #pragma unroll
    for (int k = 0; k < 8; ++k) acc[k] = 0.f;
    float den = 0.f;

    for (int base = beg; base < end; base += 64) {
        int cnt = min(64, end - base);
        float w = 0.f; int src = 0;
        if (base == beg) {
            src = src0;
            w = (lane < cnt) ? expf(v0 - m) : 0.f;
        } else {
            int i = base + lane;
            if (i < end) {
                src = csr_src[i];
                float t = ssrc[src] + sd;
                t = t > 0.f ? t : NEG_SLOPE * t;
                w = expf(t - m);
            }
        }
        den += w;
        stage[wv][lane] = make_uint2(__float_as_uint(w), (unsigned)src);
        asm volatile("s_waitcnt lgkmcnt(0)" ::: "memory");
        int steps = (cnt + 3) >> 2;
        #pragma unroll 4
        for (int j = 0; j < steps; ++j) {
            uint2 pr = stage[wv][j * 4 + g];
            float wj = __uint_as_float(pr.x);
            const uint4 hv = *(const uint4*)(hu + (size_t)pr.y * 128 + c * 8);
            FMAMIX_LO(acc[0], hv.x, wj); FMAMIX_HI(acc[1], hv.x, wj);
            FMAMIX_LO(acc[2], hv.y, wj); FMAMIX_HI(acc[3], hv.y, wj);
            FMAMIX_LO(acc[4], hv.z, wj); FMAMIX_HI(acc[5], hv.z, wj);
            FMAMIX_LO(acc[6], hv.w, wj); FMAMIX_HI(acc[7], hv.w, wj);
        }
    }
    #pragma unroll
    for (int o = 32; o; o >>= 1) den += __shfl_xor(den, o);
    #pragma unroll
    for (int k = 0; k < 8; ++k) {
        acc[k] += __shfl_xor(acc[k], 16);
        acc[k] += __shfl_xor(acc[k], 32);
    }
    if (g == 0) {
        float o8[8];
        #pragma unroll
        for (int k = 0; k < 8; ++k) {
            float v = acc[k] / den + bias[c * 8 + k];
            o8[k] = v > 0.f ? v : (expf(v) - 1.f);
        }
        float* op = out + (size_t)wid * 128 + c * 8;
        *(float4*)op       = make_float4(o8[0], o8[1], o8[2], o8[3]);
        *(float4*)(op + 4) = make_float4(o8[4], o8[5], o8[6], o8[7]);
    }
}

// ---------------- pooling (linearity: mean first, tiny GEMM after) ----------
// partial sums: 4 blocks per graph, atomicAdd into gsum[G][128]
__global__ void pool_partial(const float* __restrict__ y, const int* __restrict__ batch,
                             float* __restrict__ gsum, int n) {
    int g = blockIdx.x >> 2, seg = blockIdx.x & 3;
    int lo = 0, hi = n;
    while (lo < hi) { int mid = (lo + hi) >> 1; if (batch[mid] < g) lo = mid + 1; else hi = mid; }
    int beg = lo;
    hi = n;
    while (lo < hi) { int mid = (lo + hi) >> 1; if (batch[mid] < g + 1) lo = mid + 1; else hi = mid; }
    int end = lo;

    int c = threadIdx.x & 127, sub = threadIdx.x >> 7;
    float acc = 0.f;
    for (int node = beg + seg + 4 * sub; node < end; node += 8)
        acc += y[(size_t)node * 128 + c];

    __shared__ float ls[2][128];
    ls[sub][c] = acc;
    __syncthreads();
    if (sub == 0) atomicAdd(&gsum[g * 128 + c], ls[0][c] + ls[1][c]);
}

// out[g][oc] = (gsum[g]/cnt) @ Wlin + blin  (0 if empty graph)
__global__ void pool_final(const float* __restrict__ gsum, const int* __restrict__ batch,
                           const float* __restrict__ Wlin, const float* __restrict__ blin,
                           float* __restrict__ out, int n, int G) {
    __shared__ float Wl[128 * 32];
    __shared__ int cnts[64];
    int t = threadIdx.x;
    for (int i = t; i < 128 * 32; i += 256) Wl[i] = Wlin[i];
    if (t < G) {
        int g = t;
        int lo = 0, hi = n;
        while (lo < hi) { int mid = (lo + hi) >> 1; if (batch[mid] < g) lo = mid + 1; else hi = mid; }
        int beg = lo;
        hi = n;
        while (lo < hi) { int mid = (lo + hi) >> 1; if (batch[mid] < g + 1) lo = mid + 1; else hi = mid; }
        cnts[g] = lo - beg;
    }
    __syncthreads();
    for (int idx = t; idx < G * 32; idx += 256) {
        int g = idx >> 5, oc = idx & 31;
        int cnt = cnts[g];
        float o = 0.f;
        if (cnt > 0) {
            float inv = 1.f / (float)cnt;
            float acc = 0.f;
            #pragma unroll 8
            for (int k = 0; k < 128; ++k) acc += gsum[g * 128 + k] * Wl[k * 32 + oc];
            o = acc * inv + blin[oc];
        }
        out[idx] = o;
    }
}

extern "C" void kernel_launch(void* const* d_in, const int* in_sizes, int n_in,
                              void* d_out, int out_size, void* d_ws, size_t ws_size,
                              hipStream_t stream) {
    const float* pos  = (const float*)d_in[0];
    const int*   z    = (const int*)d_in[1];
    const int*   ei   = (const int*)d_in[2];
    const int*   batch= (const int*)d_in[3];
    const float* emb  = (const float*)d_in[4];
    const float* W1   = (const float*)d_in[5];
    const float* a1s  = (const float*)d_in[6];
    const float* a1d  = (const float*)d_in[7];
    const float* b1   = (const float*)d_in[8];
    const float* W2   = (const float*)d_in[9];
    const float* a2s  = (const float*)d_in[10];
    const float* a2d  = (const float*)d_in[11];
    const float* b2   = (const float*)d_in[12];
    const float* Wlin = (const float*)d_in[13];
    const float* blin = (const float*)d_in[14];

    const int N = in_sizes[0] / 3;        // 50000
    const int E = in_sizes[2] / 2;        // 1600000
    const int Etot = E + N;
    const int G = out_size / 32;          // 64
    const int nbins = ((N - 1) >> BIN_SHIFT) + 1;   // 196

    char* ws = (char*)d_ws;
    size_t NB = (size_t)N * 128 * sizeof(float);
    float* buf0   = (float*)ws;                    // x  (pairs aliases this)
    float* buf1   = (float*)(ws + NB);             // out2
    float* buf2   = (float*)(ws + 2 * NB);         // out1 (=x for layer2)
    float* ssrc   = (float*)(ws + 3 * NB);
    float* sdst   = ssrc + N;
    int*   rowptr = (int*)(sdst + N);              // N+1
    int*   binCnt = rowptr + N + 1;                // 256
    int*   binBase= binCnt + 256;                  // 257
    int*   binCur = binBase + 257;                 // 256
    int*   csrs   = binCur + 256;                  // Etot
    uintptr_t hp  = (uintptr_t)(csrs + Etot);
    hp = (hp + 255) & ~(uintptr_t)255;             // 256B-align for uint4 rows
    unsigned short* hbf = (unsigned short*)hp;     // N*128 f16
    float* gsum   = (float*)(hbf + (size_t)N * 128);  // G*128
    unsigned* pairs = (unsigned*)buf0;             // Etot uint (6.6MB < 25.6MB)

    const int TB = 256;
    dim3 blk(TB);
    int gElem  = (N * 128 + TB - 1) / TB;
    int gGemm  = (N + 63) / 64;
    int gGat   = (N + 3) / 4;
    int nchunk = (Etot + CHUNK - 1) / CHUNK;       // 202

    // ---------- CSR build: two-level dst binning ----------
    hipMemsetAsync(binCnt, 0, 256 * sizeof(int), stream);
    bin_hist<<<nchunk, blk, 0, stream>>>(ei, E, N, nbins, binCnt);
    bin_scan<<<1, blk, 0, stream>>>(binCnt, nbins, binBase, binCur, rowptr, N, Etot);
    bin_scatter<<<nchunk, blk, 0, stream>>>(ei, E, N, nbins, binCur, pairs);
    bin_finalize<<<nbins, blk, 0, stream>>>(pairs, binBase, rowptr, csrs, N);

    // ---------- layer 1 ----------
    build_x<<<gElem, blk, 0, stream>>>(pos, z, emb, buf0, N);
    gemm128_mfma<<<gGemm, blk, 0, stream>>>(buf0, W1, a1s, a1d, hbf, ssrc, sdst, N);
    gat_gather<<<gGat, blk, 0, stream>>>(rowptr, csrs, ssrc, sdst, hbf, b1, buf2, N);

    // ---------- layer 2 ----------
    gemm128_mfma<<<gGemm, blk, 0, stream>>>(buf2, W2, a2s, a2d, hbf, ssrc, sdst, N);
    gat_gather<<<gGat, blk, 0, stream>>>(rowptr, csrs, ssrc, sdst, hbf, b2, buf1, N);

    // ---------- pool (linearity) ----------
    hipMemsetAsync(gsum, 0, (size_t)G * 128 * sizeof(float), stream);
    pool_partial<<<G * 4, blk, 0, stream>>>(buf1, batch, gsum, N);
    pool_final<<<1, blk, 0, stream>>>(gsum, batch, Wlin, blin, (float*)d_out, N, G);
}